// Round 1
// baseline (161.320 us; speedup 1.0000x reference)
//
#include <hip/hip_runtime.h>

#define NQ 21
#define NSTATE (1u << NQ)

__device__ __forceinline__ void crot(const float2 u00, const float2 u01,
                                     const float2 u10, const float2 u11,
                                     float2& a, float2& b) {
    float2 na, nb;
    na.x = u00.x*a.x - u00.y*a.y + u01.x*b.x - u01.y*b.y;
    na.y = u00.x*a.y + u00.y*a.x + u01.x*b.y + u01.y*b.x;
    nb.x = u10.x*a.x - u10.y*a.y + u11.x*b.x - u11.y*b.y;
    nb.y = u10.x*a.y + u10.y*a.x + u11.x*b.y + u11.y*b.x;
    a = na; b = nb;
}

// Precompute all 63 Rot unitaries: Us[4*g + {00,01,10,11}]
__global__ void prep_gates(const float* __restrict__ param, float2* __restrict__ Us) {
    int g = threadIdx.x;
    if (g >= 63) return;
    float phi = param[3*g+0], th = param[3*g+1], om = param[3*g+2];
    float s, c;  __sincosf(0.5f*th, &s, &c);
    float sp, cp; __sincosf(-0.5f*(phi+om), &sp, &cp);   // ep = e^{-i(phi+om)/2}
    float sm, cm; __sincosf( 0.5f*(phi-om), &sm, &cm);   // em = e^{+i(phi-om)/2}
    Us[4*g+0] = make_float2( cp*c,  sp*c);   // ep*c
    Us[4*g+1] = make_float2(-cm*s, -sm*s);   // -em*s
    Us[4*g+2] = make_float2( cm*s, -sm*s);   // conj(em)*s
    Us[4*g+3] = make_float2( cp*c, -sp*c);   // conj(ep)*c
}

// Pass A: local bits 0..10 (qubits 10..20). 2048 contiguous amps per block.
// Rot q=10..20 then CNOT perm (evens cb=10,8,6,4,2; odds cb=9,7,5,3,1) folded
// into the store gather.
template<int LAYER, int INIT>
__global__ __launch_bounds__(256) void passA(float2* __restrict__ state,
                                             const float* __restrict__ feat,
                                             const float2* __restrict__ Us) {
    __shared__ float2 sh[2048];
    const int tid = threadIdx.x;
    const unsigned base = blockIdx.x << 11;
    if (INIT) {
        for (int i = tid; i < 2048; i += 256)
            sh[i] = make_float2(feat[base + i], 0.0f);
    } else {
        for (int i = tid; i < 2048; i += 256)
            sh[i] = state[base + i];
    }
    __syncthreads();
#pragma unroll
    for (int q = 10; q <= 20; ++q) {
        const int k = 20 - q;
        const float2 u00 = Us[4*(21*LAYER+q)+0];
        const float2 u01 = Us[4*(21*LAYER+q)+1];
        const float2 u10 = Us[4*(21*LAYER+q)+2];
        const float2 u11 = Us[4*(21*LAYER+q)+3];
        const int lm = (1<<k)-1;
        for (int p = tid; p < 1024; p += 256) {
            int i0 = ((p & ~lm) << 1) | (p & lm);
            int i1 = i0 | (1<<k);
            float2 a = sh[i0], b = sh[i1];
            crot(u00,u01,u10,u11,a,b);
            sh[i0] = a; sh[i1] = b;
        }
        __syncthreads();
    }
    // store with CNOT permutation: out[i] = sh[E(O(i))]
    for (int i = tid; i < 2048; i += 256) {
        int t = i;
        t ^= ((t>>9)&1)<<8; t ^= ((t>>7)&1)<<6; t ^= ((t>>5)&1)<<4;
        t ^= ((t>>3)&1)<<2; t ^= ((t>>1)&1)<<0;                      // odd CNOTs
        int s2 = t;
        s2 ^= ((s2>>10)&1)<<9; s2 ^= ((s2>>8)&1)<<7; s2 ^= ((s2>>6)&1)<<5;
        s2 ^= ((s2>>4)&1)<<3;  s2 ^= ((s2>>2)&1)<<1;                 // even CNOTs
        state[base + i] = sh[s2];
    }
}

// Pass B (P=10): gate bits 10..15 (qubits 5..10 partial: Rot 6..9 + 5 CNOTs)
// Pass C (P=15): gate bits 15..20 (qubits 0..5: Rot 0..5 + 5 CNOTs)
// Tile: 64 (gate-bit combos) x 64 (low bits 0..5 for coalescing) = 32 KB.
template<int LAYER, int P, int REDUCE>
__global__ __launch_bounds__(256) void passBC(float2* __restrict__ state,
                                              const float2* __restrict__ Us,
                                              float* __restrict__ out) {
    __shared__ float2 tile[64][64];
    __shared__ float wsum[4];
    const int tid = threadIdx.x;
    const unsigned f = blockIdx.x;             // 9 fixed bits
    unsigned base;
    if (P == 10) base = ((f & 15u) << 6) | ((f >> 4) << 16);
    else         base = f << 6;

    for (int idx = tid; idx < 4096; idx += 256) {
        int mid = idx >> 6, low = idx & 63;
        tile[mid][low] = state[base | ((unsigned)mid << P) | (unsigned)low];
    }
    __syncthreads();

    const int q_lo = (P == 10) ? 6 : 0;
    const int q_hi = (P == 10) ? 9 : 5;
#pragma unroll
    for (int q = q_lo; q <= q_hi; ++q) {
        const int k = (20 - q) - P;            // gate bit within tile mid-index
        const float2 u00 = Us[4*(21*LAYER+q)+0];
        const float2 u01 = Us[4*(21*LAYER+q)+1];
        const float2 u10 = Us[4*(21*LAYER+q)+2];
        const float2 u11 = Us[4*(21*LAYER+q)+3];
        const int lm = (1<<k)-1;
        for (int p = tid; p < 2048; p += 256) {
            int low = p & 63, mp = p >> 6;
            int m0 = ((mp & ~lm) << 1) | (mp & lm);
            int m1 = m0 | (1<<k);
            float2 a = tile[m0][low], b = tile[m1][low];
            crot(u00,u01,u10,u11,a,b);
            tile[m0][low] = a; tile[m1][low] = b;
        }
        __syncthreads();
    }

    if (REDUCE) {
        // final pass: sum |amp|^2 over even global indices (low bit0 == 0).
        // CNOT perm only permutes mid -> sum unaffected; skip the store.
        float acc = 0.0f;
        for (int idx = tid; idx < 4096; idx += 256) {
            int low = idx & 63;
            if (!(low & 1)) {
                float2 v = tile[idx >> 6][low];
                acc += v.x*v.x + v.y*v.y;
            }
        }
        for (int off = 32; off; off >>= 1) acc += __shfl_down(acc, off);
        if ((tid & 63) == 0) wsum[tid >> 6] = acc;
        __syncthreads();
        if (tid == 0) atomicAdd(out, wsum[0]+wsum[1]+wsum[2]+wsum[3]);
    } else {
        // store with this pass's CNOT permutation on mid: out = tile[E(O(mid))]
        for (int idx = tid; idx < 4096; idx += 256) {
            int mid = idx >> 6, low = idx & 63;
            int t = mid, s2;
            if (P == 10) {
                t ^= ((t>>5)&1)<<4; t ^= ((t>>3)&1)<<2; t ^= ((t>>1)&1)<<0;  // odds (5,6),(7,8),(9,10)
                s2 = t;
                s2 ^= ((s2>>4)&1)<<3; s2 ^= ((s2>>2)&1)<<1;                  // evens (6,7),(8,9)
            } else {
                t ^= ((t>>4)&1)<<3; t ^= ((t>>2)&1)<<1;                      // odds (1,2),(3,4)
                s2 = t;
                s2 ^= ((s2>>5)&1)<<4; s2 ^= ((s2>>3)&1)<<2; s2 ^= ((s2>>1)&1)<<0; // evens (0,1),(2,3),(4,5)
            }
            state[base | ((unsigned)mid << P) | (unsigned)low] = tile[s2][low];
        }
    }
}

extern "C" void kernel_launch(void* const* d_in, const int* in_sizes, int n_in,
                              void* d_out, int out_size, void* d_ws, size_t ws_size,
                              hipStream_t stream) {
    const float* feat  = (const float*)d_in[0];
    const float* param = (const float*)d_in[1];
    float* out = (float*)d_out;
    float2* state = (float2*)d_ws;
    float2* Us = (float2*)((char*)d_ws + (size_t)NSTATE * sizeof(float2));

    hipMemsetAsync(d_out, 0, sizeof(float), stream);
    prep_gates<<<1, 64, 0, stream>>>(param, Us);

    // layer 0
    passA<0,1><<<1024, 256, 0, stream>>>(state, feat, Us);
    passBC<0,15,0><<<512, 256, 0, stream>>>(state, Us, out);  // C: qubits 0..5
    passBC<0,10,0><<<512, 256, 0, stream>>>(state, Us, out);  // B: qubits 5..10
    // layer 1
    passA<1,0><<<1024, 256, 0, stream>>>(state, feat, Us);
    passBC<1,15,0><<<512, 256, 0, stream>>>(state, Us, out);
    passBC<1,10,0><<<512, 256, 0, stream>>>(state, Us, out);
    // layer 2
    passA<2,0><<<1024, 256, 0, stream>>>(state, feat, Us);
    passBC<2,15,0><<<512, 256, 0, stream>>>(state, Us, out);
    passBC<2,10,1><<<512, 256, 0, stream>>>(state, Us, out);  // fused reduction
}

// Round 2
// 106.426 us; speedup vs baseline: 1.5158x; 1.5158x over previous
//
#include <hip/hip_runtime.h>

#define NQ 21
#define NSTATE (1u << NQ)

// Layer CNOT permutation (evens then odds), as a gather: state_after[y] = state_before[g(y)]
// codd: flip even target bits 0..18 per odd control bit+1 ; ceven: flip odd targets 1..19 per even control bit+1
__device__ __forceinline__ unsigned cnot_perm(unsigned y) {
    unsigned t = y ^ ((y >> 1) & 0x55555u);
    return t ^ ((t >> 1) & 0xAAAAAu);
}
// LDS layout swizzle (involution): spreads bank bits with bits 7:4
__device__ __forceinline__ unsigned swz(unsigned i) { return i ^ ((i >> 4) & 0xFu); }

__device__ __forceinline__ void crot(const float2 u00, const float2 u01,
                                     const float2 u10, const float2 u11,
                                     float2& a, float2& b) {
    float2 na, nb;
    na.x = u00.x*a.x - u00.y*a.y + u01.x*b.x - u01.y*b.y;
    na.y = u00.x*a.y + u00.y*a.x + u01.x*b.y + u01.y*b.x;
    nb.x = u10.x*a.x - u10.y*a.y + u11.x*b.x - u11.y*b.y;
    nb.y = u10.x*a.y + u10.y*a.x + u11.x*b.y + u11.y*b.x;
    a = na; b = nb;
}

// apply up to 4 Rot gates on register-bits 0..3 of the 16-amp register block
template<int LAYER>
__device__ __forceinline__ void apply4(float2 v[16], const float2* __restrict__ Us,
                                       int q0, int q1, int q2, int q3) {
    const int qs[4] = {q0, q1, q2, q3};
#pragma unroll
    for (int kk = 0; kk < 4; ++kk) {
        const int q = qs[kk];
        if (q < 0) continue;
        const float2 u00 = Us[4*(21*LAYER+q)+0];
        const float2 u01 = Us[4*(21*LAYER+q)+1];
        const float2 u10 = Us[4*(21*LAYER+q)+2];
        const float2 u11 = Us[4*(21*LAYER+q)+3];
#pragma unroll
        for (int x = 0; x < 16; ++x)
            if (!(x & (1 << kk)))
                crot(u00, u01, u10, u11, v[x], v[x | (1 << kk)]);
    }
}

__global__ void prep_gates(const float* __restrict__ param, float2* __restrict__ Us) {
    int g = threadIdx.x;
    if (g >= 63) return;
    float phi = param[3*g+0], th = param[3*g+1], om = param[3*g+2];
    float s, c;  __sincosf(0.5f*th, &s, &c);
    float sp, cp; __sincosf(-0.5f*(phi+om), &sp, &cp);
    float sm, cm; __sincosf( 0.5f*(phi-om), &sm, &cm);
    Us[4*g+0] = make_float2( cp*c,  sp*c);
    Us[4*g+1] = make_float2(-cm*s, -sm*s);
    Us[4*g+2] = make_float2( cm*s, -sm*s);
    Us[4*g+3] = make_float2( cp*c, -sp*c);
}

// Sweep 1: contiguous 4096-amp region (bits 0..11 = qubits 9..20). 12 Rots in 3
// register phases. Non-INIT loads fold the previous layer's CNOT perm: source
// region is contiguous (H = high bits of g), internal 12-bit sigma gather.
template<int LAYER, int INIT>
__global__ __launch_bounds__(256) void sweep1(const float2* __restrict__ in,
                                              float2* __restrict__ out,
                                              const float* __restrict__ feat,
                                              const float2* __restrict__ Us) {
    __shared__ float2 sh[4096];
    const unsigned tid = threadIdx.x;
    const unsigned F = blockIdx.x;           // output region: bits 12..20
    float2 v[16];

    if (INIT) {
        const float4* fp = (const float4*)(feat + ((size_t)F << 12) + (tid << 4));
#pragma unroll
        for (int c = 0; c < 4; ++c) {
            float4 f = fp[c];
            v[4*c+0] = make_float2(f.x, 0.f);
            v[4*c+1] = make_float2(f.y, 0.f);
            v[4*c+2] = make_float2(f.z, 0.f);
            v[4*c+3] = make_float2(f.w, 0.f);
        }
    } else {
        const unsigned H = cnot_perm(F << 12) >> 12;   // source region (bijective)
        const float4* src = (const float4*)(in + ((size_t)H << 12));
#pragma unroll
        for (int c = 0; c < 8; ++c) {
            unsigned f = tid + (c << 8);
            float4 x = src[f];
            unsigned i = f << 1;
            sh[swz(i)]     = make_float2(x.x, x.y);
            sh[swz(i | 1)] = make_float2(x.z, x.w);
        }
        __syncthreads();
#pragma unroll
        for (int r = 0; r < 16; ++r) {
            unsigned s = cnot_perm((F << 12) | (tid << 4) | (unsigned)r) & 0xFFFu;
            v[r] = sh[swz(s)];
        }
        __syncthreads();
    }
    // phase 1: reg = e[3:0] -> qubits 20..17
    apply4<LAYER>(v, Us, 20, 19, 18, 17);
#pragma unroll
    for (int r = 0; r < 16; ++r) sh[swz((tid << 4) | (unsigned)r)] = v[r];
    __syncthreads();
    // phase 2: reg = e[7:4], thread = {e[11:8], e[3:0]} -> qubits 16..13
#pragma unroll
    for (int r = 0; r < 16; ++r)
        v[r] = sh[swz(((tid >> 4) << 8) | ((unsigned)r << 4) | (tid & 15u))];
    apply4<LAYER>(v, Us, 16, 15, 14, 13);
#pragma unroll
    for (int r = 0; r < 16; ++r)
        sh[swz(((tid >> 4) << 8) | ((unsigned)r << 4) | (tid & 15u))] = v[r];
    __syncthreads();
    // phase 3: reg = e[11:8], thread = e[7:0] -> qubits 12..9; store coalesced
#pragma unroll
    for (int r = 0; r < 16; ++r) v[r] = sh[swz(((unsigned)r << 8) | tid)];
    apply4<LAYER>(v, Us, 12, 11, 10, 9);
#pragma unroll
    for (int r = 0; r < 16; ++r)
        out[((size_t)F << 12) | ((unsigned)r << 8) | tid] = v[r];
}

// Sweep 2: tile = m(9b, bits 12..20 = qubits 0..8) x low(3b, bits 0..2), fixed
// bits 3..11 = blockIdx. 9 Rots in 3 register phases. REDUCE folds the final
// CNOT perm via the parity condition bit0^bit1^bit2==0.
template<int LAYER, int REDUCE>
__global__ __launch_bounds__(256) void sweep2(const float2* __restrict__ in,
                                              float2* __restrict__ out,
                                              float* __restrict__ res,
                                              const float2* __restrict__ Us) {
    __shared__ float2 sh[4096];
    __shared__ float wsum[4];
    const unsigned tid = threadIdx.x;
    const unsigned B = blockIdx.x;           // bits 3..11
    float2 v[16];

    const float4* inf4 = (const float4*)in;
#pragma unroll
    for (int c = 0; c < 8; ++c) {
        unsigned f = tid + (c << 8);         // 2048 float4 per tile
        unsigned m = f >> 2;
        float4 x = inf4[((size_t)m << 11) | (B << 2) | (f & 3u)];
        unsigned i = f << 1;
        sh[swz(i)]     = make_float2(x.x, x.y);
        sh[swz(i | 1)] = make_float2(x.z, x.w);
    }
    __syncthreads();
    // phase 1: reg = i[6:3] = m[3:0] -> qubits 8..5
#pragma unroll
    for (int r = 0; r < 16; ++r)
        v[r] = sh[swz(((tid >> 3) << 7) | ((unsigned)r << 3) | (tid & 7u))];
    apply4<LAYER>(v, Us, 8, 7, 6, 5);
#pragma unroll
    for (int r = 0; r < 16; ++r)
        sh[swz(((tid >> 3) << 7) | ((unsigned)r << 3) | (tid & 7u))] = v[r];
    __syncthreads();
    // phase 2: reg = i[10:7] = m[7:4] -> qubits 4..1
#pragma unroll
    for (int r = 0; r < 16; ++r)
        v[r] = sh[swz(((tid >> 7) << 11) | ((unsigned)r << 7) | (tid & 127u))];
    apply4<LAYER>(v, Us, 4, 3, 2, 1);
#pragma unroll
    for (int r = 0; r < 16; ++r)
        sh[swz(((tid >> 7) << 11) | ((unsigned)r << 7) | (tid & 127u))] = v[r];
    __syncthreads();
    // phase 3: reg = {i[11]=m[8], i[2:0]} -> qubit 0 on reg-bit 3
#pragma unroll
    for (int r = 0; r < 16; ++r)
        v[r] = sh[swz(((unsigned)(r >> 3) << 11) | (tid << 3) | ((unsigned)r & 7u))];
    apply4<LAYER>(v, Us, -1, -1, -1, 0);

    if (REDUCE) {
        float acc = 0.f;
#pragma unroll
        for (int r = 0; r < 16; ++r) {
            int l = r & 7;
            if (!((l ^ (l >> 1) ^ (l >> 2)) & 1))   // bit0^bit1^bit2 == 0
                acc += v[r].x*v[r].x + v[r].y*v[r].y;
        }
        for (int off = 32; off; off >>= 1) acc += __shfl_down(acc, off);
        if ((tid & 63u) == 0) wsum[tid >> 6] = acc;
        __syncthreads();
        if (tid == 0) atomicAdd(res, wsum[0] + wsum[1] + wsum[2] + wsum[3]);
    } else {
#pragma unroll
        for (int r = 0; r < 16; ++r)
            sh[swz(((unsigned)(r >> 3) << 11) | (tid << 3) | ((unsigned)r & 7u))] = v[r];
        __syncthreads();
        float4* outf4 = (float4*)out;
#pragma unroll
        for (int c = 0; c < 8; ++c) {
            unsigned f = tid + (c << 8);
            unsigned m = f >> 2;
            unsigned i = f << 1;
            float2 lo = sh[swz(i)], hi = sh[swz(i | 1)];
            outf4[((size_t)m << 11) | (B << 2) | (f & 3u)] = make_float4(lo.x, lo.y, hi.x, hi.y);
        }
    }
}

extern "C" void kernel_launch(void* const* d_in, const int* in_sizes, int n_in,
                              void* d_out, int out_size, void* d_ws, size_t ws_size,
                              hipStream_t stream) {
    const float* feat  = (const float*)d_in[0];
    const float* param = (const float*)d_in[1];
    float* out = (float*)d_out;
    float2* buf0 = (float2*)d_ws;
    float2* buf1 = buf0 + NSTATE;
    float2* Us   = buf1 + NSTATE;

    hipMemsetAsync(d_out, 0, sizeof(float), stream);
    prep_gates<<<1, 64, 0, stream>>>(param, Us);

    // layer 0
    sweep1<0, 1><<<512, 256, 0, stream>>>(nullptr, buf0, feat, Us);
    sweep2<0, 0><<<512, 256, 0, stream>>>(buf0, buf1, out, Us);
    // layer 1 (CNOT perm of layer 0 folded into sweep1 load)
    sweep1<1, 0><<<512, 256, 0, stream>>>(buf1, buf0, feat, Us);
    sweep2<1, 0><<<512, 256, 0, stream>>>(buf0, buf1, out, Us);
    // layer 2
    sweep1<2, 0><<<512, 256, 0, stream>>>(buf1, buf0, feat, Us);
    sweep2<2, 1><<<512, 256, 0, stream>>>(buf0, buf1, out, Us);  // fused reduce (perm via parity)
}

// Round 3
// 100.391 us; speedup vs baseline: 1.6069x; 1.0601x over previous
//
#include <hip/hip_runtime.h>
#include <hip/hip_fp16.h>

#define NQ 21
#define NSTATE (1u << NQ)

// Layer CNOT permutation (evens then odds), as a gather: state_after[y] = state_before[g(y)]
__device__ __forceinline__ unsigned cnot_perm(unsigned y) {
    unsigned t = y ^ ((y >> 1) & 0x55555u);
    return t ^ ((t >> 1) & 0xAAAAAu);
}
// LDS layout swizzle (involution): spreads bank bits with bits 7:4
__device__ __forceinline__ unsigned swz(unsigned i) { return i ^ ((i >> 4) & 0xFu); }

union H4 { int4 i4; __half2 h[4]; };

__device__ __forceinline__ void crot(const float2 u00, const float2 u01,
                                     const float2 u10, const float2 u11,
                                     float2& a, float2& b) {
    float2 na, nb;
    na.x = u00.x*a.x - u00.y*a.y + u01.x*b.x - u01.y*b.y;
    na.y = u00.x*a.y + u00.y*a.x + u01.x*b.y + u01.y*b.x;
    nb.x = u10.x*a.x - u10.y*a.y + u11.x*b.x - u11.y*b.y;
    nb.y = u10.x*a.y + u10.y*a.x + u11.x*b.y + u11.y*b.x;
    a = na; b = nb;
}

// apply up to 4 Rot gates on register-bits 0..3 of the 16-amp register block
template<int LAYER>
__device__ __forceinline__ void apply4(float2 v[16], const float2* __restrict__ Us,
                                       int q0, int q1, int q2, int q3) {
    const int qs[4] = {q0, q1, q2, q3};
#pragma unroll
    for (int kk = 0; kk < 4; ++kk) {
        const int q = qs[kk];
        if (q < 0) continue;
        const float2 u00 = Us[4*(21*LAYER+q)+0];
        const float2 u01 = Us[4*(21*LAYER+q)+1];
        const float2 u10 = Us[4*(21*LAYER+q)+2];
        const float2 u11 = Us[4*(21*LAYER+q)+3];
#pragma unroll
        for (int x = 0; x < 16; ++x)
            if (!(x & (1 << kk)))
                crot(u00, u01, u10, u11, v[x], v[x | (1 << kk)]);
    }
}

__global__ void prep_gates(const float* __restrict__ param, float2* __restrict__ Us,
                           float* __restrict__ res) {
    int g = threadIdx.x;
    if (g == 0) res[0] = 0.0f;     // replaces the 4-byte hipMemsetAsync graph node
    if (g >= 63) return;
    float phi = param[3*g+0], th = param[3*g+1], om = param[3*g+2];
    float s, c;  __sincosf(0.5f*th, &s, &c);
    float sp, cp; __sincosf(-0.5f*(phi+om), &sp, &cp);
    float sm, cm; __sincosf( 0.5f*(phi-om), &sm, &cm);
    Us[4*g+0] = make_float2( cp*c,  sp*c);
    Us[4*g+1] = make_float2(-cm*s, -sm*s);
    Us[4*g+2] = make_float2( cm*s, -sm*s);
    Us[4*g+3] = make_float2( cp*c, -sp*c);
}

// Sweep 1: contiguous 4096-amp region (bits 0..11 = qubits 9..20). 12 Rots in 3
// register phases. Non-INIT loads fold the previous layer's CNOT perm.
// State in global memory is fp16 (__half2 per amp); all math fp32.
template<int LAYER, int INIT>
__global__ __launch_bounds__(256) void sweep1(const __half2* __restrict__ in,
                                              __half2* __restrict__ out,
                                              const float* __restrict__ feat,
                                              const float2* __restrict__ Us) {
    __shared__ float2 sh[4096];
    const unsigned tid = threadIdx.x;
    const unsigned F = blockIdx.x;           // output region: bits 12..20
    float2 v[16];

    if (INIT) {
        const float4* fp = (const float4*)(feat + ((size_t)F << 12) + (tid << 4));
#pragma unroll
        for (int c = 0; c < 4; ++c) {
            float4 f = fp[c];
            v[4*c+0] = make_float2(f.x, 0.f);
            v[4*c+1] = make_float2(f.y, 0.f);
            v[4*c+2] = make_float2(f.z, 0.f);
            v[4*c+3] = make_float2(f.w, 0.f);
        }
    } else {
        const unsigned H = cnot_perm(F << 12) >> 12;   // source region (bijective)
        const int4* src = (const int4*)(in + ((size_t)H << 12));
#pragma unroll
        for (int c = 0; c < 4; ++c) {
            unsigned f = tid + (c << 8);     // 1024 int4 (4 amps each) per tile
            H4 x; x.i4 = src[f];
            unsigned i = f << 2;
            sh[swz(i)]     = __half22float2(x.h[0]);
            sh[swz(i | 1)] = __half22float2(x.h[1]);
            sh[swz(i | 2)] = __half22float2(x.h[2]);
            sh[swz(i | 3)] = __half22float2(x.h[3]);
        }
        __syncthreads();
#pragma unroll
        for (int r = 0; r < 16; ++r) {
            unsigned s = cnot_perm((F << 12) | (tid << 4) | (unsigned)r) & 0xFFFu;
            v[r] = sh[swz(s)];
        }
        __syncthreads();
    }
    // phase 1: reg = e[3:0] -> qubits 20..17
    apply4<LAYER>(v, Us, 20, 19, 18, 17);
#pragma unroll
    for (int r = 0; r < 16; ++r) sh[swz((tid << 4) | (unsigned)r)] = v[r];
    __syncthreads();
    // phase 2: reg = e[7:4], thread = {e[11:8], e[3:0]} -> qubits 16..13
#pragma unroll
    for (int r = 0; r < 16; ++r)
        v[r] = sh[swz(((tid >> 4) << 8) | ((unsigned)r << 4) | (tid & 15u))];
    apply4<LAYER>(v, Us, 16, 15, 14, 13);
#pragma unroll
    for (int r = 0; r < 16; ++r)
        sh[swz(((tid >> 4) << 8) | ((unsigned)r << 4) | (tid & 15u))] = v[r];
    __syncthreads();
    // phase 3: reg = e[11:8], thread = e[7:0] -> qubits 12..9; store coalesced
#pragma unroll
    for (int r = 0; r < 16; ++r) v[r] = sh[swz(((unsigned)r << 8) | tid)];
    apply4<LAYER>(v, Us, 12, 11, 10, 9);
#pragma unroll
    for (int r = 0; r < 16; ++r)
        out[((size_t)F << 12) | ((unsigned)r << 8) | tid] = __float22half2_rn(v[r]);
}

// Sweep 2: tile = m(9b, bits 12..20 = qubits 0..8) x low(3b, bits 0..2), fixed
// bits 3..11 = blockIdx. 9 Rots in 3 register phases. REDUCE folds the final
// CNOT perm via the parity condition bit0^bit1^bit2==0.
template<int LAYER, int REDUCE>
__global__ __launch_bounds__(256) void sweep2(const __half2* __restrict__ in,
                                              __half2* __restrict__ out,
                                              float* __restrict__ res,
                                              const float2* __restrict__ Us) {
    __shared__ float2 sh[4096];
    __shared__ float wsum[4];
    const unsigned tid = threadIdx.x;
    const unsigned B = blockIdx.x;           // bits 3..11
    float2 v[16];

    const int4* in4 = (const int4*)in;
#pragma unroll
    for (int c = 0; c < 4; ++c) {
        unsigned f = tid + (c << 8);         // 1024 int4 per tile
        unsigned m = f >> 1, j = f & 1u;
        H4 x; x.i4 = in4[((size_t)m << 10) | (B << 1) | j];
        unsigned i = f << 2;
        sh[swz(i)]     = __half22float2(x.h[0]);
        sh[swz(i | 1)] = __half22float2(x.h[1]);
        sh[swz(i | 2)] = __half22float2(x.h[2]);
        sh[swz(i | 3)] = __half22float2(x.h[3]);
    }
    __syncthreads();
    // phase 1: reg = i[6:3] = m[3:0] -> qubits 8..5
#pragma unroll
    for (int r = 0; r < 16; ++r)
        v[r] = sh[swz(((tid >> 3) << 7) | ((unsigned)r << 3) | (tid & 7u))];
    apply4<LAYER>(v, Us, 8, 7, 6, 5);
#pragma unroll
    for (int r = 0; r < 16; ++r)
        sh[swz(((tid >> 3) << 7) | ((unsigned)r << 3) | (tid & 7u))] = v[r];
    __syncthreads();
    // phase 2: reg = i[10:7] = m[7:4] -> qubits 4..1
#pragma unroll
    for (int r = 0; r < 16; ++r)
        v[r] = sh[swz(((tid >> 7) << 11) | ((unsigned)r << 7) | (tid & 127u))];
    apply4<LAYER>(v, Us, 4, 3, 2, 1);
#pragma unroll
    for (int r = 0; r < 16; ++r)
        sh[swz(((tid >> 7) << 11) | ((unsigned)r << 7) | (tid & 127u))] = v[r];
    __syncthreads();
    // phase 3: reg = {i[11]=m[8], i[2:0]} -> qubit 0 on reg-bit 3
#pragma unroll
    for (int r = 0; r < 16; ++r)
        v[r] = sh[swz(((unsigned)(r >> 3) << 11) | (tid << 3) | ((unsigned)r & 7u))];
    apply4<LAYER>(v, Us, -1, -1, -1, 0);

    if (REDUCE) {
        float acc = 0.f;
#pragma unroll
        for (int r = 0; r < 16; ++r) {
            int l = r & 7;
            if (!((l ^ (l >> 1) ^ (l >> 2)) & 1))   // bit0^bit1^bit2 == 0
                acc += v[r].x*v[r].x + v[r].y*v[r].y;
        }
        for (int off = 32; off; off >>= 1) acc += __shfl_down(acc, off);
        if ((tid & 63u) == 0) wsum[tid >> 6] = acc;
        __syncthreads();
        if (tid == 0) atomicAdd(res, wsum[0] + wsum[1] + wsum[2] + wsum[3]);
    } else {
#pragma unroll
        for (int r = 0; r < 16; ++r)
            sh[swz(((unsigned)(r >> 3) << 11) | (tid << 3) | ((unsigned)r & 7u))] = v[r];
        __syncthreads();
        int4* out4 = (int4*)out;
#pragma unroll
        for (int c = 0; c < 4; ++c) {
            unsigned f = tid + (c << 8);
            unsigned m = f >> 1, j = f & 1u;
            H4 y;
            unsigned i = f << 2;
            y.h[0] = __float22half2_rn(sh[swz(i)]);
            y.h[1] = __float22half2_rn(sh[swz(i | 1)]);
            y.h[2] = __float22half2_rn(sh[swz(i | 2)]);
            y.h[3] = __float22half2_rn(sh[swz(i | 3)]);
            out4[((size_t)m << 10) | (B << 1) | j] = y.i4;
        }
    }
}

extern "C" void kernel_launch(void* const* d_in, const int* in_sizes, int n_in,
                              void* d_out, int out_size, void* d_ws, size_t ws_size,
                              hipStream_t stream) {
    const float* feat  = (const float*)d_in[0];
    const float* param = (const float*)d_in[1];
    float* out = (float*)d_out;
    __half2* buf0 = (__half2*)d_ws;
    __half2* buf1 = buf0 + NSTATE;
    float2* Us = (float2*)(buf1 + NSTATE);

    prep_gates<<<1, 64, 0, stream>>>(param, Us, out);

    // layer 0
    sweep1<0, 1><<<512, 256, 0, stream>>>(nullptr, buf0, feat, Us);
    sweep2<0, 0><<<512, 256, 0, stream>>>(buf0, buf1, out, Us);
    // layer 1 (CNOT perm of layer 0 folded into sweep1 load)
    sweep1<1, 0><<<512, 256, 0, stream>>>(buf1, buf0, feat, Us);
    sweep2<1, 0><<<512, 256, 0, stream>>>(buf0, buf1, out, Us);
    // layer 2
    sweep1<2, 0><<<512, 256, 0, stream>>>(buf1, buf0, feat, Us);
    sweep2<2, 1><<<512, 256, 0, stream>>>(buf0, buf1, out, Us);  // fused reduce (perm via parity)
}